// Round 5
// baseline (1418.214 us; speedup 1.0000x reference)
//
#include <hip/hip_runtime.h>
#include <hip/hip_bf16.h>

#define DIM 32
#define INDIM 5
#define EPB 4096       // edges per block in bucketing passes
#define BKBITS 7
#define BKN 128        // nodes per bucket
#define NBMAX 1024     // max buckets (n <= 131072)
#define CHUNK 512      // edges staged per aggregate inner pass

// bf16 helpers (bit-level, round-to-nearest-even)
__device__ __forceinline__ unsigned short f2bf(float f) {
    unsigned u = __float_as_uint(f);
    u += 0x7FFFu + ((u >> 16) & 1u);
    return (unsigned short)(u >> 16);
}
__device__ __forceinline__ float bf2f_lo(unsigned u) { return __uint_as_float(u << 16); }
__device__ __forceinline__ float bf2f_hi(unsigned u) { return __uint_as_float(u & 0xFFFF0000u); }

// ---------------- P0: bucket sizes ----------------

__global__ __launch_bounds__(256) void bucket_count_kernel(const int* __restrict__ dst,
                                                           int* __restrict__ bcnt, int e, int nb) {
    __shared__ int hist[NBMAX];
    int t = threadIdx.x;
    for (int i = t; i < nb; i += 256) hist[i] = 0;
    __syncthreads();
    int base = blockIdx.x * EPB;
    for (int k = 0; k < EPB; k += 256) {
        int i = base + k + t;
        if (i < e) atomicAdd(&hist[dst[i] >> BKBITS], 1);
    }
    __syncthreads();
    for (int i = t; i < nb; i += 256) {
        int h = hist[i];
        if (h) atomicAdd(&bcnt[i], h);
    }
}

// ---------------- scan of bucket sizes (single block, 1024 threads) ----------------

__global__ void bucket_scan_kernel(const int* __restrict__ bcnt, int* __restrict__ bbase,
                                   int* __restrict__ bcur, int nb, int e) {
    __shared__ int s[1024];
    int t = threadIdx.x;
    int v = (t < nb) ? bcnt[t] : 0;
    s[t] = v;
    __syncthreads();
    for (int o = 1; o < 1024; o <<= 1) {
        int a = (t >= o) ? s[t - o] : 0;
        __syncthreads();
        s[t] += a;
        __syncthreads();
    }
    if (t < nb) {
        int excl = s[t] - v;
        bbase[t] = excl;
        bcur[t] = excl;
    }
    if (t == 0) bbase[nb] = e;
}

// ---------------- P1: bucketed scatter of packed edges ----------------
// packed word: (src << BKBITS) | (dst & (BKN-1))

__global__ __launch_bounds__(256) void bucket_fill_kernel(const int* __restrict__ src,
                                                          const int* __restrict__ dst,
                                                          int* __restrict__ bcur,
                                                          unsigned* __restrict__ packed,
                                                          int e, int nb) {
    __shared__ unsigned sw[EPB];
    __shared__ unsigned short sb[EPB];
    __shared__ int hist[NBMAX];
    __shared__ int rbase[NBMAX];
    int t = threadIdx.x;
    for (int i = t; i < nb; i += 256) hist[i] = 0;
    __syncthreads();
    int base = blockIdx.x * EPB;
    for (int k = 0; k < EPB; k += 256) {
        int i = base + k + t;
        if (i < e) {
            int s = src[i];
            int d = dst[i];
            int b = d >> BKBITS;
            sw[k + t] = ((unsigned)s << BKBITS) | (unsigned)(d & (BKN - 1));
            sb[k + t] = (unsigned short)b;
            atomicAdd(&hist[b], 1);
        }
    }
    __syncthreads();
    for (int i = t; i < nb; i += 256) {
        int h = hist[i];
        rbase[i] = h ? atomicAdd(&bcur[i], h) : 0;
        hist[i] = 0;  // reuse as rank counter
    }
    __syncthreads();
    for (int k = 0; k < EPB; k += 256) {
        int i = base + k + t;
        if (i < e) {
            int b = sb[k + t];
            int r = atomicAdd(&hist[b], 1);
            packed[rbase[b] + r] = sw[k + t];
        }
    }
}

// ---------------- deg: per-node inverse degree from packed ----------------

__global__ __launch_bounds__(256) void deg_kernel(const unsigned* __restrict__ packed,
                                                  const int* __restrict__ bbase,
                                                  float* __restrict__ inv_deg, int n) {
    __shared__ int cnt[BKN];
    int b = blockIdx.x, t = threadIdx.x;
    if (t < BKN) cnt[t] = 0;
    __syncthreads();
    int bs = bbase[b], be = bbase[b + 1];
    for (int i = bs + t; i < be; i += 256) atomicAdd(&cnt[packed[i] & (BKN - 1)], 1);
    __syncthreads();
    int node = b * BKN + t;
    if (t < BKN && node < n) inv_deg[node] = 1.f / fmaxf((float)cnt[t], 1.f);
}

// ---------------- input projection: h = x @ w_in.T + b_in (bf16 out) ----------------

__global__ void input_proj_kernel(const float* __restrict__ x, const float* __restrict__ w_in,
                                  const float* __restrict__ b_in,
                                  unsigned short* __restrict__ h, int n) {
    __shared__ float sw[DIM * INDIM];
    __shared__ float sb[DIM];
    int t = threadIdx.x;
    if (t < DIM * INDIM) sw[t] = w_in[t];
    if (t < DIM) sb[t] = b_in[t];
    __syncthreads();
    int idx = blockIdx.x * 256 + t;
    int node = idx >> 5;
    int d = idx & 31;
    if (node < n) {
        const float* xr = x + (size_t)node * INDIM;
        float acc = sb[d];
#pragma unroll
        for (int k = 0; k < INDIM; k++) acc = fmaf(xr[k], sw[d * INDIM + k], acc);
        h[(size_t)node * DIM + d] = f2bf(acc);
    }
}

// ---------------- Phase A: edge-parallel mean aggregate into LDS ----------------
// one block per 128-node bucket; 8 lanes per edge (uint2 = 4 bf16 dims each);
// fp32 LDS accumulator with ds_add atomics; agg written fp32 (agg buffer = d_out).

__global__ __launch_bounds__(256) void aggregate_kernel(
    const unsigned* __restrict__ packed, const int* __restrict__ bbase,
    const unsigned short* __restrict__ h_in, const float* __restrict__ inv_deg,
    float* __restrict__ agg, int n) {
    __shared__ float sAgg[BKN][DIM + 1];  // +1 pad: spreads banks for atomics
    __shared__ unsigned sE[CHUNK];
    int b = blockIdx.x, t = threadIdx.x;
    for (int i = t; i < BKN * (DIM + 1); i += 256) (&sAgg[0][0])[i] = 0.f;
    int bs = bbase[b], be = bbase[b + 1];
    int sub = t & 7;  // which uint2 of the row
    const uint2* hv = (const uint2*)h_in;
    for (int cb = bs; cb < be; cb += CHUNK) {
        int m = be - cb;
        if (m > CHUNK) m = CHUNK;
        __syncthreads();  // also covers zero-init on first iter / prev-pass reads
        for (int i = t; i < m; i += 256) sE[i] = packed[cb + i];
        __syncthreads();
#pragma unroll
        for (int q = 0; q < CHUNK / 32; q++) {
            int k = (t >> 3) + q * 32;
            if (k < m) {
                unsigned w = sE[k];
                int srcn = (int)(w >> BKBITS);
                int dl = (int)(w & (BKN - 1));
                uint2 v = hv[(size_t)srcn * 8 + sub];
                float* ap = &sAgg[dl][sub * 4];
                atomicAdd(&ap[0], bf2f_lo(v.x));
                atomicAdd(&ap[1], bf2f_hi(v.x));
                atomicAdd(&ap[2], bf2f_lo(v.y));
                atomicAdd(&ap[3], bf2f_hi(v.y));
            }
        }
    }
    __syncthreads();
    int base_node = b * BKN;
    for (int i = t; i < BKN * (DIM / 2); i += 256) {
        int nd = i >> 4, pp = i & 15;
        int node = base_node + nd;
        if (node < n) {
            float iv = inv_deg[node];
            float2 f;
            f.x = sAgg[nd][pp * 2] * iv;
            f.y = sAgg[nd][pp * 2 + 1] * iv;
            *(float2*)&agg[(size_t)node * DIM + pp * 2] = f;
        }
    }
}

// ---------------- Phase B: node-parallel combine + ReLU + LayerNorm ----------------
// thread = (node, dim); weights for both matrices live in registers; vectors via LDS.
// For LAST: reads agg rows (== d_out) into LDS, then overwrites them in place.

template <int LAST>
__global__ __launch_bounds__(256) void combine_kernel(
    const float* __restrict__ agg, const unsigned short* __restrict__ h_in,
    unsigned short* __restrict__ h_out_bf, float* __restrict__ out_f32,
    const float* __restrict__ wl, const float* __restrict__ bl,
    const float* __restrict__ wr, const float* __restrict__ gamma,
    const float* __restrict__ beta, int n, int ngroups) {
    __shared__ float sVec[8][2][DIM];  // [node][agg|self][dim]
    int t = threadIdx.x;
    int d = t & 31;
    float wlr[DIM], wrr[DIM];
    {
        const float4* p1 = (const float4*)(wl + (size_t)d * DIM);
        const float4* p2 = (const float4*)(wr + (size_t)d * DIM);
#pragma unroll
        for (int q = 0; q < 8; q++) {
            float4 a = p1[q];
            wlr[4 * q] = a.x; wlr[4 * q + 1] = a.y; wlr[4 * q + 2] = a.z; wlr[4 * q + 3] = a.w;
            float4 c = p2[q];
            wrr[4 * q] = c.x; wrr[4 * q + 1] = c.y; wrr[4 * q + 2] = c.z; wrr[4 * q + 3] = c.w;
        }
    }
    float bias = bl[d], g = gamma[d], be = beta[d];
    for (int grp = blockIdx.x; grp < ngroups; grp += gridDim.x) {
        int nb8 = grp * 8;
        __syncthreads();  // protect sVec reuse across iterations
        if (t < 64) {
            int nd = t >> 3, q = t & 7;
            int node = nb8 + nd;
            float4 f = make_float4(0.f, 0.f, 0.f, 0.f);
            if (node < n) f = ((const float4*)agg)[(size_t)node * 8 + q];
            *(float4*)&sVec[nd][0][q * 4] = f;
        } else if (t < 128) {
            int tt = t - 64, nd = tt >> 3, q = tt & 7;
            int node = nb8 + nd;
            uint2 v = make_uint2(0u, 0u);
            if (node < n) v = ((const uint2*)h_in)[(size_t)node * 8 + q];
            float4 f;
            f.x = bf2f_lo(v.x); f.y = bf2f_hi(v.x);
            f.z = bf2f_lo(v.y); f.w = bf2f_hi(v.y);
            *(float4*)&sVec[nd][1][q * 4] = f;
        }
        __syncthreads();
        int nd = t >> 5;  // 0..7
        int node = nb8 + nd;
        if (node < n) {
            float o = bias;
            const float* va = sVec[nd][0];
            const float* vs = sVec[nd][1];
#pragma unroll
            for (int q = 0; q < 8; q++) {
                float4 a = *(const float4*)&va[q * 4];
                float4 s = *(const float4*)&vs[q * 4];
                o = fmaf(a.x, wlr[4 * q], o);     o = fmaf(s.x, wrr[4 * q], o);
                o = fmaf(a.y, wlr[4 * q + 1], o); o = fmaf(s.y, wrr[4 * q + 1], o);
                o = fmaf(a.z, wlr[4 * q + 2], o); o = fmaf(s.z, wrr[4 * q + 2], o);
                o = fmaf(a.w, wlr[4 * q + 3], o); o = fmaf(s.w, wrr[4 * q + 3], o);
            }
            float out = fmaxf(o, 0.f);
            float sum = out, sq = out * out;
#pragma unroll
            for (int off = 16; off > 0; off >>= 1) {
                sum += __shfl_xor(sum, off, 32);
                sq += __shfl_xor(sq, off, 32);
            }
            float mu = sum * (1.f / 32.f);
            float var = fmaxf(sq * (1.f / 32.f) - mu * mu, 0.f);
            float r = rsqrtf(var + 1e-5f);
            float res = (out - mu) * r * g + be;
            if (LAST) out_f32[(size_t)node * DIM + d] = res;
            else      h_out_bf[(size_t)node * DIM + d] = f2bf(res);
        }
    }
}

// ---------------- launch ----------------

extern "C" void kernel_launch(void* const* d_in, const int* in_sizes, int n_in,
                              void* d_out, int out_size, void* d_ws, size_t ws_size,
                              hipStream_t stream) {
    const float* x = (const float*)d_in[0];
    const int* ei = (const int*)d_in[1];
    const float* w_in = (const float*)d_in[2];
    const float* b_in = (const float*)d_in[3];
    const float* w_l = (const float*)d_in[4];
    const float* b_l = (const float*)d_in[5];
    const float* w_r = (const float*)d_in[6];
    const float* gamma = (const float*)d_in[7];
    const float* beta = (const float*)d_in[8];

    int n = in_sizes[0] / INDIM;
    int e = in_sizes[1] / 2;
    int L = in_sizes[4] / (DIM * DIM);
    const int* src = ei;
    const int* dst = ei + e;
    int nb = (n + BKN - 1) >> BKBITS;  // 128-node buckets (782 for N=100000)

    // workspace carve (~21.2 MB)
    char* w = (char*)d_ws;
    int* bcnt = (int*)w;               w += (size_t)NBMAX * 4;
    int* bbase = (int*)w;              w += (size_t)(NBMAX + 1) * 4;
    int* bcur = (int*)w;               w += (size_t)NBMAX * 4;
    float* inv_deg = (float*)w;        w += (size_t)n * 4;
    unsigned* packed = (unsigned*)w;   w += (size_t)e * 4;
    unsigned short* h_A = (unsigned short*)w;  w += (size_t)n * DIM * 2;
    unsigned short* h_B = (unsigned short*)w;  w += (size_t)n * DIM * 2;

    // fp32 agg buffer aliases d_out (dead until the final combine, which
    // reads agg rows into LDS before overwriting them in place)
    float* aggf = (float*)d_out;

    int nbE = (e + EPB - 1) / EPB;

    hipMemsetAsync(bcnt, 0, (size_t)nb * 4, stream);
    bucket_count_kernel<<<nbE, 256, 0, stream>>>(dst, bcnt, e, nb);
    bucket_scan_kernel<<<1, 1024, 0, stream>>>(bcnt, bbase, bcur, nb, e);
    bucket_fill_kernel<<<nbE, 256, 0, stream>>>(src, dst, bcur, packed, e, nb);
    deg_kernel<<<nb, 256, 0, stream>>>(packed, bbase, inv_deg, n);

    input_proj_kernel<<<(n * DIM + 255) / 256, 256, 0, stream>>>(x, w_in, b_in, h_A, n);

    // L=3: A->B, B->A, A->d_out
    unsigned short* bufs[2] = {h_A, h_B};
    int ngroups = (n + 7) / 8;
    for (int i = 0; i < L; i++) {
        const unsigned short* hin = bufs[i & 1];
        unsigned short* hout = bufs[(i + 1) & 1];
        const float* wl = w_l + (size_t)i * DIM * DIM;
        const float* bl = b_l + (size_t)i * DIM;
        const float* wr = w_r + (size_t)i * DIM * DIM;
        aggregate_kernel<<<nb, 256, 0, stream>>>(packed, bbase, hin, inv_deg, aggf, n);
        if (i == L - 1)
            combine_kernel<1><<<1024, 256, 0, stream>>>(aggf, hin, nullptr, (float*)d_out,
                                                        wl, bl, wr, gamma, beta, n, ngroups);
        else
            combine_kernel<0><<<1024, 256, 0, stream>>>(aggf, hin, hout, nullptr,
                                                        wl, bl, wr, gamma, beta, n, ngroups);
    }
}

// Round 6
// 1179.024 us; speedup vs baseline: 1.2029x; 1.2029x over previous
//
#include <hip/hip_runtime.h>
#include <hip/hip_bf16.h>

#define DIM 32
#define INDIM 5
#define EPB 4096       // edges per block in bucketing passes
#define BKBITS 7
#define BKN 128        // nodes per bucket
#define NBMAX 1024     // max buckets (n <= 131072)
#define SPLIT 4        // dim-slices per bucket (8 dims each)

// bf16 helpers (bit-level, round-to-nearest-even)
__device__ __forceinline__ unsigned short f2bf(float f) {
    unsigned u = __float_as_uint(f);
    u += 0x7FFFu + ((u >> 16) & 1u);
    return (unsigned short)(u >> 16);
}
__device__ __forceinline__ float bf2f_lo(unsigned u) { return __uint_as_float(u << 16); }
__device__ __forceinline__ float bf2f_hi(unsigned u) { return __uint_as_float(u & 0xFFFF0000u); }

// ---------------- P0: bucket sizes ----------------

__global__ __launch_bounds__(256) void bucket_count_kernel(const int* __restrict__ dst,
                                                           int* __restrict__ bcnt, int e, int nb) {
    __shared__ int hist[NBMAX];
    int t = threadIdx.x;
    for (int i = t; i < nb; i += 256) hist[i] = 0;
    __syncthreads();
    int base = blockIdx.x * EPB;
    for (int k = 0; k < EPB; k += 256) {
        int i = base + k + t;
        if (i < e) atomicAdd(&hist[dst[i] >> BKBITS], 1);
    }
    __syncthreads();
    for (int i = t; i < nb; i += 256) {
        int h = hist[i];
        if (h) atomicAdd(&bcnt[i], h);
    }
}

// ---------------- scan of bucket sizes (single block, 1024 threads) ----------------

__global__ void bucket_scan_kernel(const int* __restrict__ bcnt, int* __restrict__ bbase,
                                   int* __restrict__ bcur, int nb, int e) {
    __shared__ int s[1024];
    int t = threadIdx.x;
    int v = (t < nb) ? bcnt[t] : 0;
    s[t] = v;
    __syncthreads();
    for (int o = 1; o < 1024; o <<= 1) {
        int a = (t >= o) ? s[t - o] : 0;
        __syncthreads();
        s[t] += a;
        __syncthreads();
    }
    if (t < nb) {
        int excl = s[t] - v;
        bbase[t] = excl;
        bcur[t] = excl;
    }
    if (t == 0) bbase[nb] = e;
}

// ---------------- P1: bucketed scatter of packed edges ----------------
// packed word: (src << BKBITS) | (dst & (BKN-1))

__global__ __launch_bounds__(256) void bucket_fill_kernel(const int* __restrict__ src,
                                                          const int* __restrict__ dst,
                                                          int* __restrict__ bcur,
                                                          unsigned* __restrict__ packed,
                                                          int e, int nb) {
    __shared__ unsigned sw[EPB];
    __shared__ unsigned short sb[EPB];
    __shared__ int hist[NBMAX];
    __shared__ int rbase[NBMAX];
    int t = threadIdx.x;
    for (int i = t; i < nb; i += 256) hist[i] = 0;
    __syncthreads();
    int base = blockIdx.x * EPB;
    for (int k = 0; k < EPB; k += 256) {
        int i = base + k + t;
        if (i < e) {
            int s = src[i];
            int d = dst[i];
            int b = d >> BKBITS;
            sw[k + t] = ((unsigned)s << BKBITS) | (unsigned)(d & (BKN - 1));
            sb[k + t] = (unsigned short)b;
            atomicAdd(&hist[b], 1);
        }
    }
    __syncthreads();
    for (int i = t; i < nb; i += 256) {
        int h = hist[i];
        rbase[i] = h ? atomicAdd(&bcur[i], h) : 0;
        hist[i] = 0;  // reuse as rank counter
    }
    __syncthreads();
    for (int k = 0; k < EPB; k += 256) {
        int i = base + k + t;
        if (i < e) {
            int b = sb[k + t];
            int r = atomicAdd(&hist[b], 1);
            packed[rbase[b] + r] = sw[k + t];
        }
    }
}

// ---------------- deg: per-node inverse degree from packed ----------------

__global__ __launch_bounds__(256) void deg_kernel(const unsigned* __restrict__ packed,
                                                  const int* __restrict__ bbase,
                                                  float* __restrict__ inv_deg, int n) {
    __shared__ int cnt[BKN];
    int b = blockIdx.x, t = threadIdx.x;
    if (t < BKN) cnt[t] = 0;
    __syncthreads();
    int bs = bbase[b], be = bbase[b + 1];
    for (int i = bs + t; i < be; i += 256) atomicAdd(&cnt[packed[i] & (BKN - 1)], 1);
    __syncthreads();
    int node = b * BKN + t;
    if (t < BKN && node < n) inv_deg[node] = 1.f / fmaxf((float)cnt[t], 1.f);
}

// ---------------- input projection: h = x @ w_in.T + b_in (bf16 out) ----------------

__global__ void input_proj_kernel(const float* __restrict__ x, const float* __restrict__ w_in,
                                  const float* __restrict__ b_in,
                                  unsigned short* __restrict__ h, int n) {
    __shared__ float sw[DIM * INDIM];
    __shared__ float sb[DIM];
    int t = threadIdx.x;
    if (t < DIM * INDIM) sw[t] = w_in[t];
    if (t < DIM) sb[t] = b_in[t];
    __syncthreads();
    int idx = blockIdx.x * 256 + t;
    int node = idx >> 5;
    int d = idx & 31;
    if (node < n) {
        const float* xr = x + (size_t)node * INDIM;
        float acc = sb[d];
#pragma unroll
        for (int k = 0; k < INDIM; k++) acc = fmaf(xr[k], sw[d * INDIM + k], acc);
        h[(size_t)node * DIM + d] = f2bf(acc);
    }
}

// ---------------- Phase A: edge-parallel mean aggregate (dim-sliced) ----------------
// grid = nb * SPLIT. Block (bucket b, slice sub) owns dims [sub*8, sub*8+8) of the
// 128 bucket rows: tiny LDS accumulator, 1 thread per edge per pass (256 random
// 16B row-slice loads in flight), 8 short LDS atomics each, plain-store writeout.

__global__ __launch_bounds__(256) void aggregate_kernel(
    const unsigned* __restrict__ packed, const int* __restrict__ bbase,
    const unsigned short* __restrict__ h_in, const float* __restrict__ inv_deg,
    float* __restrict__ agg, int n) {
    __shared__ float sAgg[BKN][9];  // 8 dims + pad
    int b = blockIdx.x >> 2;
    int sub = blockIdx.x & 3;
    int t = threadIdx.x;
    for (int i = t; i < BKN * 9; i += 256) (&sAgg[0][0])[i] = 0.f;
    __syncthreads();
    int bs = bbase[b], be = bbase[b + 1];
    const uint4* hv = (const uint4*)h_in;  // row = 4 x uint4 (64B); slice sub = 16B
    // 2-deep software pipeline: prefetch next pass's packed word
    int i1 = bs + t;
    unsigned w1 = (i1 < be) ? packed[i1] : 0xFFFFFFFFu;
    for (int cb = bs; cb < be; cb += 256) {
        unsigned w0 = w1;
        bool val = (w0 != 0xFFFFFFFFu);
        uint4 v = make_uint4(0u, 0u, 0u, 0u);
        if (val) v = hv[(size_t)(w0 >> BKBITS) * 4 + sub];
        int i2 = cb + 256 + t;
        w1 = (i2 < be) ? packed[i2] : 0xFFFFFFFFu;
        if (val) {
            float* ap = &sAgg[w0 & (BKN - 1)][0];
            atomicAdd(&ap[0], bf2f_lo(v.x));
            atomicAdd(&ap[1], bf2f_hi(v.x));
            atomicAdd(&ap[2], bf2f_lo(v.y));
            atomicAdd(&ap[3], bf2f_hi(v.y));
            atomicAdd(&ap[4], bf2f_lo(v.z));
            atomicAdd(&ap[5], bf2f_hi(v.z));
            atomicAdd(&ap[6], bf2f_lo(v.w));
            atomicAdd(&ap[7], bf2f_hi(v.w));
        }
    }
    __syncthreads();
    // writeout: 128 nodes x 8 dims (this slice), scaled by inv_deg
    int nd = t >> 1, half = t & 1;
    int node = b * BKN + nd;
    if (node < n) {
        float iv = inv_deg[node];
        float4 f;
        f.x = sAgg[nd][half * 4 + 0] * iv;
        f.y = sAgg[nd][half * 4 + 1] * iv;
        f.z = sAgg[nd][half * 4 + 2] * iv;
        f.w = sAgg[nd][half * 4 + 3] * iv;
        *(float4*)&agg[(size_t)node * DIM + sub * 8 + half * 4] = f;
    }
}

// ---------------- Phase B: node-parallel combine + ReLU + LayerNorm ----------------
// thread = (node, dim); weights for both matrices live in registers; vectors via LDS.
// For LAST: reads agg rows (== d_out) into LDS, then overwrites them in place.

template <int LAST>
__global__ __launch_bounds__(256) void combine_kernel(
    const float* __restrict__ agg, const unsigned short* __restrict__ h_in,
    unsigned short* __restrict__ h_out_bf, float* __restrict__ out_f32,
    const float* __restrict__ wl, const float* __restrict__ bl,
    const float* __restrict__ wr, const float* __restrict__ gamma,
    const float* __restrict__ beta, int n, int ngroups) {
    __shared__ float sVec[8][2][DIM];  // [node][agg|self][dim]
    int t = threadIdx.x;
    int d = t & 31;
    float wlr[DIM], wrr[DIM];
    {
        const float4* p1 = (const float4*)(wl + (size_t)d * DIM);
        const float4* p2 = (const float4*)(wr + (size_t)d * DIM);
#pragma unroll
        for (int q = 0; q < 8; q++) {
            float4 a = p1[q];
            wlr[4 * q] = a.x; wlr[4 * q + 1] = a.y; wlr[4 * q + 2] = a.z; wlr[4 * q + 3] = a.w;
            float4 c = p2[q];
            wrr[4 * q] = c.x; wrr[4 * q + 1] = c.y; wrr[4 * q + 2] = c.z; wrr[4 * q + 3] = c.w;
        }
    }
    float bias = bl[d], g = gamma[d], be = beta[d];
    for (int grp = blockIdx.x; grp < ngroups; grp += gridDim.x) {
        int nb8 = grp * 8;
        __syncthreads();  // protect sVec reuse across iterations
        if (t < 64) {
            int nd = t >> 3, q = t & 7;
            int node = nb8 + nd;
            float4 f = make_float4(0.f, 0.f, 0.f, 0.f);
            if (node < n) f = ((const float4*)agg)[(size_t)node * 8 + q];
            *(float4*)&sVec[nd][0][q * 4] = f;
        } else if (t < 128) {
            int tt = t - 64, nd = tt >> 3, q = tt & 7;
            int node = nb8 + nd;
            uint2 v = make_uint2(0u, 0u);
            if (node < n) v = ((const uint2*)h_in)[(size_t)node * 8 + q];
            float4 f;
            f.x = bf2f_lo(v.x); f.y = bf2f_hi(v.x);
            f.z = bf2f_lo(v.y); f.w = bf2f_hi(v.y);
            *(float4*)&sVec[nd][1][q * 4] = f;
        }
        __syncthreads();
        int nd = t >> 5;  // 0..7
        int node = nb8 + nd;
        if (node < n) {
            float o = bias;
            const float* va = sVec[nd][0];
            const float* vs = sVec[nd][1];
#pragma unroll
            for (int q = 0; q < 8; q++) {
                float4 a = *(const float4*)&va[q * 4];
                float4 s = *(const float4*)&vs[q * 4];
                o = fmaf(a.x, wlr[4 * q], o);     o = fmaf(s.x, wrr[4 * q], o);
                o = fmaf(a.y, wlr[4 * q + 1], o); o = fmaf(s.y, wrr[4 * q + 1], o);
                o = fmaf(a.z, wlr[4 * q + 2], o); o = fmaf(s.z, wrr[4 * q + 2], o);
                o = fmaf(a.w, wlr[4 * q + 3], o); o = fmaf(s.w, wrr[4 * q + 3], o);
            }
            float out = fmaxf(o, 0.f);
            float sum = out, sq = out * out;
#pragma unroll
            for (int off = 16; off > 0; off >>= 1) {
                sum += __shfl_xor(sum, off, 32);
                sq += __shfl_xor(sq, off, 32);
            }
            float mu = sum * (1.f / 32.f);
            float var = fmaxf(sq * (1.f / 32.f) - mu * mu, 0.f);
            float r = rsqrtf(var + 1e-5f);
            float res = (out - mu) * r * g + be;
            if (LAST) out_f32[(size_t)node * DIM + d] = res;
            else      h_out_bf[(size_t)node * DIM + d] = f2bf(res);
        }
    }
}

// ---------------- launch ----------------

extern "C" void kernel_launch(void* const* d_in, const int* in_sizes, int n_in,
                              void* d_out, int out_size, void* d_ws, size_t ws_size,
                              hipStream_t stream) {
    const float* x = (const float*)d_in[0];
    const int* ei = (const int*)d_in[1];
    const float* w_in = (const float*)d_in[2];
    const float* b_in = (const float*)d_in[3];
    const float* w_l = (const float*)d_in[4];
    const float* b_l = (const float*)d_in[5];
    const float* w_r = (const float*)d_in[6];
    const float* gamma = (const float*)d_in[7];
    const float* beta = (const float*)d_in[8];

    int n = in_sizes[0] / INDIM;
    int e = in_sizes[1] / 2;
    int L = in_sizes[4] / (DIM * DIM);
    const int* src = ei;
    const int* dst = ei + e;
    int nb = (n + BKN - 1) >> BKBITS;  // 128-node buckets (782 for N=100000)

    // workspace carve (~21.2 MB)
    char* w = (char*)d_ws;
    int* bcnt = (int*)w;               w += (size_t)NBMAX * 4;
    int* bbase = (int*)w;              w += (size_t)(NBMAX + 1) * 4;
    int* bcur = (int*)w;               w += (size_t)NBMAX * 4;
    float* inv_deg = (float*)w;        w += (size_t)n * 4;
    unsigned* packed = (unsigned*)w;   w += (size_t)e * 4;
    unsigned short* h_A = (unsigned short*)w;  w += (size_t)n * DIM * 2;
    unsigned short* h_B = (unsigned short*)w;  w += (size_t)n * DIM * 2;

    // fp32 agg buffer aliases d_out (dead until the final combine, which
    // reads agg rows into LDS before overwriting them in place)
    float* aggf = (float*)d_out;

    int nbE = (e + EPB - 1) / EPB;

    hipMemsetAsync(bcnt, 0, (size_t)nb * 4, stream);
    bucket_count_kernel<<<nbE, 256, 0, stream>>>(dst, bcnt, e, nb);
    bucket_scan_kernel<<<1, 1024, 0, stream>>>(bcnt, bbase, bcur, nb, e);
    bucket_fill_kernel<<<nbE, 256, 0, stream>>>(src, dst, bcur, packed, e, nb);
    deg_kernel<<<nb, 256, 0, stream>>>(packed, bbase, inv_deg, n);

    input_proj_kernel<<<(n * DIM + 255) / 256, 256, 0, stream>>>(x, w_in, b_in, h_A, n);

    // L=3: A->B, B->A, A->d_out
    unsigned short* bufs[2] = {h_A, h_B};
    int ngroups = (n + 7) / 8;
    for (int i = 0; i < L; i++) {
        const unsigned short* hin = bufs[i & 1];
        unsigned short* hout = bufs[(i + 1) & 1];
        const float* wl = w_l + (size_t)i * DIM * DIM;
        const float* bl = b_l + (size_t)i * DIM;
        const float* wr = w_r + (size_t)i * DIM * DIM;
        aggregate_kernel<<<nb * SPLIT, 256, 0, stream>>>(packed, bbase, hin, inv_deg, aggf, n);
        if (i == L - 1)
            combine_kernel<1><<<1024, 256, 0, stream>>>(aggf, hin, nullptr, (float*)d_out,
                                                        wl, bl, wr, gamma, beta, n, ngroups);
        else
            combine_kernel<0><<<1024, 256, 0, stream>>>(aggf, hin, hout, nullptr,
                                                        wl, bl, wr, gamma, beta, n, ngroups);
    }
}

// Round 7
// 268.087 us; speedup vs baseline: 5.2901x; 4.3979x over previous
//
#include <hip/hip_runtime.h>
#include <hip/hip_bf16.h>

#define DIM 32
#define INDIM 5
#define EPB 4096      // edges per block in bucketing passes
#define NBMAX 512     // max buckets (n <= 131072), 256-node buckets
#define CAP 8192      // P2 LDS staging capacity (mean bucket load ~5120)

// bf16 helpers (bit-level, round-to-nearest-even)
__device__ __forceinline__ unsigned short f2bf(float f) {
    unsigned u = __float_as_uint(f);
    u += 0x7FFFu + ((u >> 16) & 1u);
    return (unsigned short)(u >> 16);
}
__device__ __forceinline__ float bf2f_lo(unsigned u) { return __uint_as_float(u << 16); }
__device__ __forceinline__ float bf2f_hi(unsigned u) { return __uint_as_float(u & 0xFFFF0000u); }

// ---------------- P0: bucket sizes ----------------

__global__ __launch_bounds__(256) void bucket_count_kernel(const int* __restrict__ dst,
                                                           int* __restrict__ bcnt, int e, int nb) {
    __shared__ int hist[NBMAX];
    int t = threadIdx.x;
    for (int i = t; i < nb; i += 256) hist[i] = 0;
    __syncthreads();
    int base = blockIdx.x * EPB;
    for (int k = 0; k < EPB; k += 256) {
        int i = base + k + t;
        if (i < e) atomicAdd(&hist[dst[i] >> 8], 1);
    }
    __syncthreads();
    for (int i = t; i < nb; i += 256) {
        int h = hist[i];
        if (h) atomicAdd(&bcnt[i], h);
    }
}

// ---------------- scan of bucket sizes (single block, 512 threads) ----------------

__global__ void bucket_scan_kernel(const int* __restrict__ bcnt, int* __restrict__ bbase,
                                   int* __restrict__ bcur, int* __restrict__ row_ptr,
                                   int nb, int n, int e) {
    __shared__ int s[512];
    int t = threadIdx.x;
    int v = (t < nb) ? bcnt[t] : 0;
    s[t] = v;
    __syncthreads();
    for (int o = 1; o < 512; o <<= 1) {
        int a = (t >= o) ? s[t - o] : 0;
        __syncthreads();
        s[t] += a;
        __syncthreads();
    }
    if (t < nb) {
        int excl = s[t] - v;
        bbase[t] = excl;
        bcur[t] = excl;
    }
    if (t == 0) {
        bbase[nb] = e;
        row_ptr[n] = e;
    }
}

// ---------------- P1: bucketed scatter of packed edges ----------------
// packed word: (src << 8) | (dst & 255)

__global__ __launch_bounds__(256) void bucket_fill_kernel(const int* __restrict__ src,
                                                          const int* __restrict__ dst,
                                                          int* __restrict__ bcur,
                                                          unsigned* __restrict__ packed,
                                                          int e, int nb) {
    __shared__ unsigned sw[EPB];
    __shared__ unsigned short sb[EPB];
    __shared__ int hist[NBMAX];
    __shared__ int rbase[NBMAX];
    int t = threadIdx.x;
    for (int i = t; i < nb; i += 256) hist[i] = 0;
    __syncthreads();
    int base = blockIdx.x * EPB;
    for (int k = 0; k < EPB; k += 256) {
        int i = base + k + t;
        if (i < e) {
            int s = src[i];
            int d = dst[i];
            int b = d >> 8;
            sw[k + t] = ((unsigned)s << 8) | (unsigned)(d & 255);
            sb[k + t] = (unsigned short)b;
            atomicAdd(&hist[b], 1);
        }
    }
    __syncthreads();
    for (int i = t; i < nb; i += 256) {
        int h = hist[i];
        rbase[i] = h ? atomicAdd(&bcur[i], h) : 0;
        hist[i] = 0;  // reuse as rank counter
    }
    __syncthreads();
    for (int k = 0; k < EPB; k += 256) {
        int i = base + k + t;
        if (i < e) {
            int b = sb[k + t];
            int r = atomicAdd(&hist[b], 1);
            packed[rbase[b] + r] = sw[k + t];
        }
    }
}

// ---------------- P2: per-bucket counting sort -> exact CSR ----------------

__global__ __launch_bounds__(256) void csr_build_kernel(const unsigned* __restrict__ packed,
                                                        const int* __restrict__ bbase,
                                                        int* __restrict__ row_ptr,
                                                        int* __restrict__ esrc, int n) {
    __shared__ unsigned ew[CAP];
    __shared__ int h2[256];
    __shared__ int off[256];
    int b = blockIdx.x;
    int base = bbase[b];
    int cnt = bbase[b + 1] - base;
    int t = threadIdx.x;
    h2[t] = 0;
    __syncthreads();
    bool staged = (cnt <= CAP);
    for (int i = t; i < cnt; i += 256) {
        unsigned w = packed[base + i];
        if (staged) ew[i] = w;
        atomicAdd(&h2[w & 255], 1);
    }
    __syncthreads();
    int v = h2[t];
    off[t] = v;
    __syncthreads();
    for (int o = 1; o < 256; o <<= 1) {
        int a = (t >= o) ? off[t - o] : 0;
        __syncthreads();
        off[t] += a;
        __syncthreads();
    }
    int excl = off[t] - v;
    __syncthreads();
    off[t] = excl;
    h2[t] = 0;  // reuse as rank counter
    __syncthreads();
    int node = b * 256 + t;
    if (node < n) row_ptr[node] = base + excl;
    for (int i = t; i < cnt; i += 256) {
        unsigned w = staged ? ew[i] : packed[base + i];
        int dl = w & 255;
        int r = atomicAdd(&h2[dl], 1);
        esrc[base + off[dl] + r] = (int)(w >> 8);
    }
}

// ---------------- input projection: h = x @ w_in.T + b_in (bf16 out) ----------------

__global__ void input_proj_kernel(const float* __restrict__ x, const float* __restrict__ w_in,
                                  const float* __restrict__ b_in,
                                  unsigned short* __restrict__ h, int n) {
    __shared__ float sw[DIM * INDIM];
    __shared__ float sb[DIM];
    int t = threadIdx.x;
    if (t < DIM * INDIM) sw[t] = w_in[t];
    if (t < DIM) sb[t] = b_in[t];
    __syncthreads();
    int idx = blockIdx.x * 256 + t;
    int node = idx >> 5;
    int d = idx & 31;
    if (node < n) {
        const float* xr = x + (size_t)node * INDIM;
        float acc = sb[d];
#pragma unroll
        for (int k = 0; k < INDIM; k++) acc = fmaf(xr[k], sw[d * INDIM + k], acc);
        h[(size_t)node * DIM + d] = f2bf(acc);
    }
}

// ---------------- Phase A: pull-model mean aggregate, no cross-lane ops ----------------
// 4 threads per node; thread q owns dims [8q, 8q+8) (uint4 = 16 B of the 64 B row).
// Neighbor loop unrolled 4-wide -> 16 independent gathers in flight per group.
// No LDS, no shuffles, no atomics. agg fp32 (aliases d_out).

__global__ __launch_bounds__(256) void aggregate_kernel(
    const int* __restrict__ row_ptr, const int* __restrict__ esrc,
    const unsigned short* __restrict__ h_in, float* __restrict__ agg, int n) {
    int t = threadIdx.x;
    int node = blockIdx.x * 64 + (t >> 2);
    if (node >= n) return;
    int q = t & 3;
    int rs = row_ptr[node];
    int re = row_ptr[node + 1];
    const uint4* hv = (const uint4*)h_in;  // row = 4 x uint4

    float a0 = 0.f, a1 = 0.f, a2 = 0.f, a3 = 0.f, a4 = 0.f, a5 = 0.f, a6 = 0.f, a7 = 0.f;
    int j = rs;
    for (; j + 4 <= re; j += 4) {
        int s0 = esrc[j], s1 = esrc[j + 1], s2 = esrc[j + 2], s3 = esrc[j + 3];
        uint4 v0 = hv[(size_t)s0 * 4 + q];
        uint4 v1 = hv[(size_t)s1 * 4 + q];
        uint4 v2 = hv[(size_t)s2 * 4 + q];
        uint4 v3 = hv[(size_t)s3 * 4 + q];
        a0 += bf2f_lo(v0.x); a1 += bf2f_hi(v0.x); a2 += bf2f_lo(v0.y); a3 += bf2f_hi(v0.y);
        a4 += bf2f_lo(v0.z); a5 += bf2f_hi(v0.z); a6 += bf2f_lo(v0.w); a7 += bf2f_hi(v0.w);
        a0 += bf2f_lo(v1.x); a1 += bf2f_hi(v1.x); a2 += bf2f_lo(v1.y); a3 += bf2f_hi(v1.y);
        a4 += bf2f_lo(v1.z); a5 += bf2f_hi(v1.z); a6 += bf2f_lo(v1.w); a7 += bf2f_hi(v1.w);
        a0 += bf2f_lo(v2.x); a1 += bf2f_hi(v2.x); a2 += bf2f_lo(v2.y); a3 += bf2f_hi(v2.y);
        a4 += bf2f_lo(v2.z); a5 += bf2f_hi(v2.z); a6 += bf2f_lo(v2.w); a7 += bf2f_hi(v2.w);
        a0 += bf2f_lo(v3.x); a1 += bf2f_hi(v3.x); a2 += bf2f_lo(v3.y); a3 += bf2f_hi(v3.y);
        a4 += bf2f_lo(v3.z); a5 += bf2f_hi(v3.z); a6 += bf2f_lo(v3.w); a7 += bf2f_hi(v3.w);
    }
    for (; j < re; ++j) {
        int s = esrc[j];
        uint4 v = hv[(size_t)s * 4 + q];
        a0 += bf2f_lo(v.x); a1 += bf2f_hi(v.x); a2 += bf2f_lo(v.y); a3 += bf2f_hi(v.y);
        a4 += bf2f_lo(v.z); a5 += bf2f_hi(v.z); a6 += bf2f_lo(v.w); a7 += bf2f_hi(v.w);
    }
    float iv = 1.f / fmaxf((float)(re - rs), 1.f);
    float* ap = agg + (size_t)node * DIM + q * 8;
    float4 f0 = make_float4(a0 * iv, a1 * iv, a2 * iv, a3 * iv);
    float4 f1 = make_float4(a4 * iv, a5 * iv, a6 * iv, a7 * iv);
    *(float4*)(ap) = f0;
    *(float4*)(ap + 4) = f1;
}

// ---------------- Phase B: node-parallel combine + ReLU + LayerNorm ----------------
// thread = (node, dim); weights for both matrices live in registers; vectors via LDS.
// For LAST: reads agg rows (== d_out) into LDS, then overwrites them in place.

template <int LAST>
__global__ __launch_bounds__(256) void combine_kernel(
    const float* __restrict__ agg, const unsigned short* __restrict__ h_in,
    unsigned short* __restrict__ h_out_bf, float* __restrict__ out_f32,
    const float* __restrict__ wl, const float* __restrict__ bl,
    const float* __restrict__ wr, const float* __restrict__ gamma,
    const float* __restrict__ beta, int n, int ngroups) {
    __shared__ float sVec[8][2][DIM];  // [node][agg|self][dim]
    int t = threadIdx.x;
    int d = t & 31;
    float wlr[DIM], wrr[DIM];
    {
        const float4* p1 = (const float4*)(wl + (size_t)d * DIM);
        const float4* p2 = (const float4*)(wr + (size_t)d * DIM);
#pragma unroll
        for (int q = 0; q < 8; q++) {
            float4 a = p1[q];
            wlr[4 * q] = a.x; wlr[4 * q + 1] = a.y; wlr[4 * q + 2] = a.z; wlr[4 * q + 3] = a.w;
            float4 c = p2[q];
            wrr[4 * q] = c.x; wrr[4 * q + 1] = c.y; wrr[4 * q + 2] = c.z; wrr[4 * q + 3] = c.w;
        }
    }
    float bias = bl[d], g = gamma[d], be = beta[d];
    for (int grp = blockIdx.x; grp < ngroups; grp += gridDim.x) {
        int nb8 = grp * 8;
        __syncthreads();  // protect sVec reuse across iterations
        if (t < 64) {
            int nd = t >> 3, q = t & 7;
            int node = nb8 + nd;
            float4 f = make_float4(0.f, 0.f, 0.f, 0.f);
            if (node < n) f = ((const float4*)agg)[(size_t)node * 8 + q];
            *(float4*)&sVec[nd][0][q * 4] = f;
        } else if (t < 128) {
            int tt = t - 64, nd = tt >> 3, q = tt & 7;
            int node = nb8 + nd;
            uint2 v = make_uint2(0u, 0u);
            if (node < n) v = ((const uint2*)h_in)[(size_t)node * 8 + q];
            float4 f;
            f.x = bf2f_lo(v.x); f.y = bf2f_hi(v.x);
            f.z = bf2f_lo(v.y); f.w = bf2f_hi(v.y);
            *(float4*)&sVec[nd][1][q * 4] = f;
        }
        __syncthreads();
        int nd = t >> 5;  // 0..7
        int node = nb8 + nd;
        if (node < n) {
            float o = bias;
            const float* va = sVec[nd][0];
            const float* vs = sVec[nd][1];
#pragma unroll
            for (int q = 0; q < 8; q++) {
                float4 a = *(const float4*)&va[q * 4];
                float4 s = *(const float4*)&vs[q * 4];
                o = fmaf(a.x, wlr[4 * q], o);     o = fmaf(s.x, wrr[4 * q], o);
                o = fmaf(a.y, wlr[4 * q + 1], o); o = fmaf(s.y, wrr[4 * q + 1], o);
                o = fmaf(a.z, wlr[4 * q + 2], o); o = fmaf(s.z, wrr[4 * q + 2], o);
                o = fmaf(a.w, wlr[4 * q + 3], o); o = fmaf(s.w, wrr[4 * q + 3], o);
            }
            float out = fmaxf(o, 0.f);
            float sum = out, sq = out * out;
#pragma unroll
            for (int off = 16; off > 0; off >>= 1) {
                sum += __shfl_xor(sum, off, 32);
                sq += __shfl_xor(sq, off, 32);
            }
            float mu = sum * (1.f / 32.f);
            float var = fmaxf(sq * (1.f / 32.f) - mu * mu, 0.f);
            float r = rsqrtf(var + 1e-5f);
            float res = (out - mu) * r * g + be;
            if (LAST) out_f32[(size_t)node * DIM + d] = res;
            else      h_out_bf[(size_t)node * DIM + d] = f2bf(res);
        }
    }
}

// ---------------- launch ----------------

extern "C" void kernel_launch(void* const* d_in, const int* in_sizes, int n_in,
                              void* d_out, int out_size, void* d_ws, size_t ws_size,
                              hipStream_t stream) {
    const float* x = (const float*)d_in[0];
    const int* ei = (const int*)d_in[1];
    const float* w_in = (const float*)d_in[2];
    const float* b_in = (const float*)d_in[3];
    const float* w_l = (const float*)d_in[4];
    const float* b_l = (const float*)d_in[5];
    const float* w_r = (const float*)d_in[6];
    const float* gamma = (const float*)d_in[7];
    const float* beta = (const float*)d_in[8];

    int n = in_sizes[0] / INDIM;
    int e = in_sizes[1] / 2;
    int L = in_sizes[4] / (DIM * DIM);
    const int* src = ei;
    const int* dst = ei + e;
    int nb = (n + 255) >> 8;  // 256-node buckets (391 for N=100000)

    // workspace carve (~21.7 MB)
    char* w = (char*)d_ws;
    int* bcnt = (int*)w;               w += (size_t)NBMAX * 4;
    int* bbase = (int*)w;              w += (size_t)(NBMAX + 1) * 4;
    int* bcur = (int*)w;               w += (size_t)NBMAX * 4;
    int* row_ptr = (int*)w;            w += (size_t)(n + 1) * 4;
    int* esrc = (int*)w;               w += (size_t)e * 4;
    unsigned short* h_A = (unsigned short*)w;  w += (size_t)n * DIM * 2;
    unsigned short* h_B = (unsigned short*)w;  w += (size_t)n * DIM * 2;
    // packed (E*4 = 8 MB) aliases h_A+h_B (12.8 MB): dead before input_proj
    unsigned* packed = (unsigned*)h_A;
    // fp32 agg buffer aliases d_out (dead until the final combine, which
    // reads agg rows into LDS before overwriting them in place)
    float* aggf = (float*)d_out;

    int nbE = (e + EPB - 1) / EPB;

    hipMemsetAsync(bcnt, 0, (size_t)nb * 4, stream);
    bucket_count_kernel<<<nbE, 256, 0, stream>>>(dst, bcnt, e, nb);
    bucket_scan_kernel<<<1, 512, 0, stream>>>(bcnt, bbase, bcur, row_ptr, nb, n, e);
    bucket_fill_kernel<<<nbE, 256, 0, stream>>>(src, dst, bcur, packed, e, nb);
    csr_build_kernel<<<nb, 256, 0, stream>>>(packed, bbase, row_ptr, esrc, n);

    input_proj_kernel<<<(n * DIM + 255) / 256, 256, 0, stream>>>(x, w_in, b_in, h_A, n);

    // L=3: A->B, B->A, A->d_out
    unsigned short* bufs[2] = {h_A, h_B};
    int ngroups = (n + 7) / 8;
    int nbA = (n + 63) / 64;
    for (int i = 0; i < L; i++) {
        const unsigned short* hin = bufs[i & 1];
        unsigned short* hout = bufs[(i + 1) & 1];
        const float* wl = w_l + (size_t)i * DIM * DIM;
        const float* bl = b_l + (size_t)i * DIM;
        const float* wr = w_r + (size_t)i * DIM * DIM;
        aggregate_kernel<<<nbA, 256, 0, stream>>>(row_ptr, esrc, hin, aggf, n);
        if (i == L - 1)
            combine_kernel<1><<<1024, 256, 0, stream>>>(aggf, hin, nullptr, (float*)d_out,
                                                        wl, bl, wr, gamma, beta, n, ngroups);
        else
            combine_kernel<0><<<1024, 256, 0, stream>>>(aggf, hin, hout, nullptr,
                                                        wl, bl, wr, gamma, beta, n, ngroups);
    }
}

// Round 8
// 252.110 us; speedup vs baseline: 5.6254x; 1.0634x over previous
//
#include <hip/hip_runtime.h>
#include <hip/hip_bf16.h>

#define DIM 32
#define INDIM 5
#define EPB 4096      // edges per block in bucketing passes
#define NBMAX 512     // max buckets (n <= 131072), 256-node buckets
#define CAP 8192      // P2 LDS staging capacity (mean bucket load ~5120)

// bf16 helpers (bit-level, round-to-nearest-even)
__device__ __forceinline__ unsigned short f2bf(float f) {
    unsigned u = __float_as_uint(f);
    u += 0x7FFFu + ((u >> 16) & 1u);
    return (unsigned short)(u >> 16);
}
__device__ __forceinline__ float bf2f_lo(unsigned u) { return __uint_as_float(u << 16); }
__device__ __forceinline__ float bf2f_hi(unsigned u) { return __uint_as_float(u & 0xFFFF0000u); }

// ---------------- P0: bucket sizes ----------------

__global__ __launch_bounds__(256) void bucket_count_kernel(const int* __restrict__ dst,
                                                           int* __restrict__ bcnt, int e, int nb) {
    __shared__ int hist[NBMAX];
    int t = threadIdx.x;
    for (int i = t; i < nb; i += 256) hist[i] = 0;
    __syncthreads();
    int base = blockIdx.x * EPB;
    for (int k = 0; k < EPB; k += 256) {
        int i = base + k + t;
        if (i < e) atomicAdd(&hist[dst[i] >> 8], 1);
    }
    __syncthreads();
    for (int i = t; i < nb; i += 256) {
        int h = hist[i];
        if (h) atomicAdd(&bcnt[i], h);
    }
}

// ---------------- scan of bucket sizes (single block, 512 threads) ----------------

__global__ void bucket_scan_kernel(const int* __restrict__ bcnt, int* __restrict__ bbase,
                                   int* __restrict__ bcur, int* __restrict__ row_ptr,
                                   int nb, int n, int e) {
    __shared__ int s[512];
    int t = threadIdx.x;
    int v = (t < nb) ? bcnt[t] : 0;
    s[t] = v;
    __syncthreads();
    for (int o = 1; o < 512; o <<= 1) {
        int a = (t >= o) ? s[t - o] : 0;
        __syncthreads();
        s[t] += a;
        __syncthreads();
    }
    if (t < nb) {
        int excl = s[t] - v;
        bbase[t] = excl;
        bcur[t] = excl;
    }
    if (t == 0) {
        bbase[nb] = e;
        row_ptr[n] = e;
    }
}

// ---------------- P1: bucketed scatter of packed edges ----------------
// packed word: (src << 8) | (dst & 255)

__global__ __launch_bounds__(256) void bucket_fill_kernel(const int* __restrict__ src,
                                                          const int* __restrict__ dst,
                                                          int* __restrict__ bcur,
                                                          unsigned* __restrict__ packed,
                                                          int e, int nb) {
    __shared__ unsigned sw[EPB];
    __shared__ unsigned short sb[EPB];
    __shared__ int hist[NBMAX];
    __shared__ int rbase[NBMAX];
    int t = threadIdx.x;
    for (int i = t; i < nb; i += 256) hist[i] = 0;
    __syncthreads();
    int base = blockIdx.x * EPB;
    for (int k = 0; k < EPB; k += 256) {
        int i = base + k + t;
        if (i < e) {
            int s = src[i];
            int d = dst[i];
            int b = d >> 8;
            sw[k + t] = ((unsigned)s << 8) | (unsigned)(d & 255);
            sb[k + t] = (unsigned short)b;
            atomicAdd(&hist[b], 1);
        }
    }
    __syncthreads();
    for (int i = t; i < nb; i += 256) {
        int h = hist[i];
        rbase[i] = h ? atomicAdd(&bcur[i], h) : 0;
        hist[i] = 0;  // reuse as rank counter
    }
    __syncthreads();
    for (int k = 0; k < EPB; k += 256) {
        int i = base + k + t;
        if (i < e) {
            int b = sb[k + t];
            int r = atomicAdd(&hist[b], 1);
            packed[rbase[b] + r] = sw[k + t];
        }
    }
}

// ---------------- P2: per-bucket counting sort -> exact CSR ----------------

__global__ __launch_bounds__(256) void csr_build_kernel(const unsigned* __restrict__ packed,
                                                        const int* __restrict__ bbase,
                                                        int* __restrict__ row_ptr,
                                                        int* __restrict__ esrc, int n) {
    __shared__ unsigned ew[CAP];
    __shared__ int h2[256];
    __shared__ int off[256];
    int b = blockIdx.x;
    int base = bbase[b];
    int cnt = bbase[b + 1] - base;
    int t = threadIdx.x;
    h2[t] = 0;
    __syncthreads();
    bool staged = (cnt <= CAP);
    for (int i = t; i < cnt; i += 256) {
        unsigned w = packed[base + i];
        if (staged) ew[i] = w;
        atomicAdd(&h2[w & 255], 1);
    }
    __syncthreads();
    int v = h2[t];
    off[t] = v;
    __syncthreads();
    for (int o = 1; o < 256; o <<= 1) {
        int a = (t >= o) ? off[t - o] : 0;
        __syncthreads();
        off[t] += a;
        __syncthreads();
    }
    int excl = off[t] - v;
    __syncthreads();
    off[t] = excl;
    h2[t] = 0;  // reuse as rank counter
    __syncthreads();
    int node = b * 256 + t;
    if (node < n) row_ptr[node] = base + excl;
    for (int i = t; i < cnt; i += 256) {
        unsigned w = staged ? ew[i] : packed[base + i];
        int dl = w & 255;
        int r = atomicAdd(&h2[dl], 1);
        esrc[base + off[dl] + r] = (int)(w >> 8);
    }
}

// ---------------- input projection: h = x @ w_in.T + b_in (bf16 out) ----------------

__global__ void input_proj_kernel(const float* __restrict__ x, const float* __restrict__ w_in,
                                  const float* __restrict__ b_in,
                                  unsigned short* __restrict__ h, int n) {
    __shared__ float sw[DIM * INDIM];
    __shared__ float sb[DIM];
    int t = threadIdx.x;
    if (t < DIM * INDIM) sw[t] = w_in[t];
    if (t < DIM) sb[t] = b_in[t];
    __syncthreads();
    int idx = blockIdx.x * 256 + t;
    int node = idx >> 5;
    int d = idx & 31;
    if (node < n) {
        const float* xr = x + (size_t)node * INDIM;
        float acc = sb[d];
#pragma unroll
        for (int k = 0; k < INDIM; k++) acc = fmaf(xr[k], sw[d * INDIM + k], acc);
        h[(size_t)node * DIM + d] = f2bf(acc);
    }
}

// ---------------- fused layer: gather-mean + SAGEConv + ReLU + LayerNorm ----------------
// 64 nodes/block. Phase 1: 4 threads/node (thread q owns dims [8q,8q+8)), 8-wide
// unrolled pull gather, mean into LDS. Phase 2: dual matvec with both weight
// matrices in registers (thread = dim), ReLU + LN, direct store.

template <int LAST>
__global__ __launch_bounds__(256, 4) void layer_fused_kernel(
    const int* __restrict__ row_ptr, const int* __restrict__ esrc,
    const unsigned short* __restrict__ h_in,
    unsigned short* __restrict__ h_out_bf, float* __restrict__ out_f32,
    const float* __restrict__ wl, const float* __restrict__ bl,
    const float* __restrict__ wr, const float* __restrict__ gamma,
    const float* __restrict__ beta, int n) {
    __shared__ float sAgg[64][DIM];
    __shared__ float sSelf[64][DIM];

    int t = threadIdx.x;
    int d = t & 31;

    // weight rows in registers (64 VGPR)
    float wlr[DIM], wrr[DIM];
    {
        const float4* p1 = (const float4*)(wl + (size_t)d * DIM);
        const float4* p2 = (const float4*)(wr + (size_t)d * DIM);
#pragma unroll
        for (int qq = 0; qq < 8; qq++) {
            float4 a = p1[qq];
            wlr[4 * qq] = a.x; wlr[4 * qq + 1] = a.y; wlr[4 * qq + 2] = a.z; wlr[4 * qq + 3] = a.w;
            float4 c = p2[qq];
            wrr[4 * qq] = c.x; wrr[4 * qq + 1] = c.y; wrr[4 * qq + 2] = c.z; wrr[4 * qq + 3] = c.w;
        }
    }
    float bias = bl[d], g = gamma[d], be = beta[d];

    // ---- phase 1: gather ----
    int nd = t >> 2;  // 0..63
    int q = t & 3;
    int node = blockIdx.x * 64 + nd;
    const uint4* hv = (const uint4*)h_in;  // row = 4 x uint4 (64 B)

    if (node < n) {
        // self row slice
        {
            uint4 v = hv[(size_t)node * 4 + q];
            float4 f0 = make_float4(bf2f_lo(v.x), bf2f_hi(v.x), bf2f_lo(v.y), bf2f_hi(v.y));
            float4 f1 = make_float4(bf2f_lo(v.z), bf2f_hi(v.z), bf2f_lo(v.w), bf2f_hi(v.w));
            *(float4*)&sSelf[nd][q * 8] = f0;
            *(float4*)&sSelf[nd][q * 8 + 4] = f1;
        }
        int rs = row_ptr[node];
        int re = row_ptr[node + 1];
        float a0 = 0.f, a1 = 0.f, a2 = 0.f, a3 = 0.f, a4 = 0.f, a5 = 0.f, a6 = 0.f, a7 = 0.f;
        int j = rs;
        for (; j + 8 <= re; j += 8) {
            int s0 = esrc[j], s1 = esrc[j + 1], s2 = esrc[j + 2], s3 = esrc[j + 3];
            int s4 = esrc[j + 4], s5 = esrc[j + 5], s6 = esrc[j + 6], s7 = esrc[j + 7];
            uint4 v0 = hv[(size_t)s0 * 4 + q];
            uint4 v1 = hv[(size_t)s1 * 4 + q];
            uint4 v2 = hv[(size_t)s2 * 4 + q];
            uint4 v3 = hv[(size_t)s3 * 4 + q];
            uint4 v4 = hv[(size_t)s4 * 4 + q];
            uint4 v5 = hv[(size_t)s5 * 4 + q];
            uint4 v6 = hv[(size_t)s6 * 4 + q];
            uint4 v7 = hv[(size_t)s7 * 4 + q];
            a0 += bf2f_lo(v0.x); a1 += bf2f_hi(v0.x); a2 += bf2f_lo(v0.y); a3 += bf2f_hi(v0.y);
            a4 += bf2f_lo(v0.z); a5 += bf2f_hi(v0.z); a6 += bf2f_lo(v0.w); a7 += bf2f_hi(v0.w);
            a0 += bf2f_lo(v1.x); a1 += bf2f_hi(v1.x); a2 += bf2f_lo(v1.y); a3 += bf2f_hi(v1.y);
            a4 += bf2f_lo(v1.z); a5 += bf2f_hi(v1.z); a6 += bf2f_lo(v1.w); a7 += bf2f_hi(v1.w);
            a0 += bf2f_lo(v2.x); a1 += bf2f_hi(v2.x); a2 += bf2f_lo(v2.y); a3 += bf2f_hi(v2.y);
            a4 += bf2f_lo(v2.z); a5 += bf2f_hi(v2.z); a6 += bf2f_lo(v2.w); a7 += bf2f_hi(v2.w);
            a0 += bf2f_lo(v3.x); a1 += bf2f_hi(v3.x); a2 += bf2f_lo(v3.y); a3 += bf2f_hi(v3.y);
            a4 += bf2f_lo(v3.z); a5 += bf2f_hi(v3.z); a6 += bf2f_lo(v3.w); a7 += bf2f_hi(v3.w);
            a0 += bf2f_lo(v4.x); a1 += bf2f_hi(v4.x); a2 += bf2f_lo(v4.y); a3 += bf2f_hi(v4.y);
            a4 += bf2f_lo(v4.z); a5 += bf2f_hi(v4.z); a6 += bf2f_lo(v4.w); a7 += bf2f_hi(v4.w);
            a0 += bf2f_lo(v5.x); a1 += bf2f_hi(v5.x); a2 += bf2f_lo(v5.y); a3 += bf2f_hi(v5.y);
            a4 += bf2f_lo(v5.z); a5 += bf2f_hi(v5.z); a6 += bf2f_lo(v5.w); a7 += bf2f_hi(v5.w);
            a0 += bf2f_lo(v6.x); a1 += bf2f_hi(v6.x); a2 += bf2f_lo(v6.y); a3 += bf2f_hi(v6.y);
            a4 += bf2f_lo(v6.z); a5 += bf2f_hi(v6.z); a6 += bf2f_lo(v6.w); a7 += bf2f_hi(v6.w);
            a0 += bf2f_lo(v7.x); a1 += bf2f_hi(v7.x); a2 += bf2f_lo(v7.y); a3 += bf2f_hi(v7.y);
            a4 += bf2f_lo(v7.z); a5 += bf2f_hi(v7.z); a6 += bf2f_lo(v7.w); a7 += bf2f_hi(v7.w);
        }
        for (; j < re; ++j) {
            int s = esrc[j];
            uint4 v = hv[(size_t)s * 4 + q];
            a0 += bf2f_lo(v.x); a1 += bf2f_hi(v.x); a2 += bf2f_lo(v.y); a3 += bf2f_hi(v.y);
            a4 += bf2f_lo(v.z); a5 += bf2f_hi(v.z); a6 += bf2f_lo(v.w); a7 += bf2f_hi(v.w);
        }
        float iv = 1.f / fmaxf((float)(re - rs), 1.f);
        float4 f0 = make_float4(a0 * iv, a1 * iv, a2 * iv, a3 * iv);
        float4 f1 = make_float4(a4 * iv, a5 * iv, a6 * iv, a7 * iv);
        *(float4*)&sAgg[nd][q * 8] = f0;
        *(float4*)&sAgg[nd][q * 8 + 4] = f1;
    }
    __syncthreads();

    // ---- phase 2: combine + ReLU + LN ----
#pragma unroll
    for (int it = 0; it < 8; ++it) {
        int ln = it * 8 + (t >> 5);           // local node 0..63
        int nodec = blockIdx.x * 64 + ln;
        if (nodec < n) {
            float o = bias;
            const float* va = sAgg[ln];
            const float* vs = sSelf[ln];
#pragma unroll
            for (int qq = 0; qq < 8; qq++) {
                float4 a = *(const float4*)&va[qq * 4];
                float4 s = *(const float4*)&vs[qq * 4];
                o = fmaf(a.x, wlr[4 * qq], o);     o = fmaf(s.x, wrr[4 * qq], o);
                o = fmaf(a.y, wlr[4 * qq + 1], o); o = fmaf(s.y, wrr[4 * qq + 1], o);
                o = fmaf(a.z, wlr[4 * qq + 2], o); o = fmaf(s.z, wrr[4 * qq + 2], o);
                o = fmaf(a.w, wlr[4 * qq + 3], o); o = fmaf(s.w, wrr[4 * qq + 3], o);
            }
            float out = fmaxf(o, 0.f);
            float sum = out, sq = out * out;
#pragma unroll
            for (int off = 16; off > 0; off >>= 1) {
                sum += __shfl_xor(sum, off, 32);
                sq += __shfl_xor(sq, off, 32);
            }
            float mu = sum * (1.f / 32.f);
            float var = fmaxf(sq * (1.f / 32.f) - mu * mu, 0.f);
            float r = rsqrtf(var + 1e-5f);
            float res = (out - mu) * r * g + be;
            if (LAST) out_f32[(size_t)nodec * DIM + d] = res;
            else      h_out_bf[(size_t)nodec * DIM + d] = f2bf(res);
        }
    }
}

// ---------------- launch ----------------

extern "C" void kernel_launch(void* const* d_in, const int* in_sizes, int n_in,
                              void* d_out, int out_size, void* d_ws, size_t ws_size,
                              hipStream_t stream) {
    const float* x = (const float*)d_in[0];
    const int* ei = (const int*)d_in[1];
    const float* w_in = (const float*)d_in[2];
    const float* b_in = (const float*)d_in[3];
    const float* w_l = (const float*)d_in[4];
    const float* b_l = (const float*)d_in[5];
    const float* w_r = (const float*)d_in[6];
    const float* gamma = (const float*)d_in[7];
    const float* beta = (const float*)d_in[8];

    int n = in_sizes[0] / INDIM;
    int e = in_sizes[1] / 2;
    int L = in_sizes[4] / (DIM * DIM);
    const int* src = ei;
    const int* dst = ei + e;
    int nb = (n + 255) >> 8;  // 256-node buckets (391 for N=100000)

    // workspace carve (~21.7 MB)
    char* w = (char*)d_ws;
    int* bcnt = (int*)w;               w += (size_t)NBMAX * 4;
    int* bbase = (int*)w;              w += (size_t)(NBMAX + 1) * 4;
    int* bcur = (int*)w;               w += (size_t)NBMAX * 4;
    int* row_ptr = (int*)w;            w += (size_t)(n + 1) * 4;
    int* esrc = (int*)w;               w += (size_t)e * 4;
    unsigned short* h_A = (unsigned short*)w;  w += (size_t)n * DIM * 2;
    unsigned short* h_B = (unsigned short*)w;  w += (size_t)n * DIM * 2;
    // packed (E*4 = 8 MB) aliases h_A+h_B (12.8 MB): dead before input_proj
    unsigned* packed = (unsigned*)h_A;

    int nbE = (e + EPB - 1) / EPB;

    hipMemsetAsync(bcnt, 0, (size_t)nb * 4, stream);
    bucket_count_kernel<<<nbE, 256, 0, stream>>>(dst, bcnt, e, nb);
    bucket_scan_kernel<<<1, 512, 0, stream>>>(bcnt, bbase, bcur, row_ptr, nb, n, e);
    bucket_fill_kernel<<<nbE, 256, 0, stream>>>(src, dst, bcur, packed, e, nb);
    csr_build_kernel<<<nb, 256, 0, stream>>>(packed, bbase, row_ptr, esrc, n);

    input_proj_kernel<<<(n * DIM + 255) / 256, 256, 0, stream>>>(x, w_in, b_in, h_A, n);

    // L=3: A->B, B->A, A->d_out
    unsigned short* bufs[2] = {h_A, h_B};
    int nbF = (n + 63) / 64;
    for (int i = 0; i < L; i++) {
        const unsigned short* hin = bufs[i & 1];
        unsigned short* hout = bufs[(i + 1) & 1];
        const float* wl = w_l + (size_t)i * DIM * DIM;
        const float* bl = b_l + (size_t)i * DIM;
        const float* wr = w_r + (size_t)i * DIM * DIM;
        if (i == L - 1)
            layer_fused_kernel<1><<<nbF, 256, 0, stream>>>(row_ptr, esrc, hin, nullptr,
                                                           (float*)d_out, wl, bl, wr,
                                                           gamma, beta, n);
        else
            layer_fused_kernel<0><<<nbF, 256, 0, stream>>>(row_ptr, esrc, hin, hout,
                                                           nullptr, wl, bl, wr,
                                                           gamma, beta, n);
    }
}

// Round 9
// 242.201 us; speedup vs baseline: 5.8555x; 1.0409x over previous
//
#include <hip/hip_runtime.h>
#include <hip/hip_bf16.h>

#define DIM 32
#define INDIM 5
#define EPB 4096      // edges per block in bucketing passes
#define BKBITS 7
#define BKN 128       // nodes per bucket
#define NBMAX 1024    // max buckets (n <= 131072)
#define CAP 4096      // P2 LDS staging capacity (mean bucket load ~2560)

// bf16 helpers (bit-level, round-to-nearest-even)
__device__ __forceinline__ unsigned short f2bf(float f) {
    unsigned u = __float_as_uint(f);
    u += 0x7FFFu + ((u >> 16) & 1u);
    return (unsigned short)(u >> 16);
}
__device__ __forceinline__ float bf2f_lo(unsigned u) { return __uint_as_float(u << 16); }
__device__ __forceinline__ float bf2f_hi(unsigned u) { return __uint_as_float(u & 0xFFFF0000u); }

// ---------------- P0: bucket sizes ----------------

__global__ __launch_bounds__(256) void bucket_count_kernel(const int* __restrict__ dst,
                                                           int* __restrict__ bcnt, int e, int nb) {
    __shared__ int hist[NBMAX];
    int t = threadIdx.x;
    for (int i = t; i < nb; i += 256) hist[i] = 0;
    __syncthreads();
    int base = blockIdx.x * EPB;
    for (int k = 0; k < EPB; k += 256) {
        int i = base + k + t;
        if (i < e) atomicAdd(&hist[dst[i] >> BKBITS], 1);
    }
    __syncthreads();
    for (int i = t; i < nb; i += 256) {
        int h = hist[i];
        if (h) atomicAdd(&bcnt[i], h);
    }
}

// ---------------- scan of bucket sizes (single block, 1024 threads) ----------------

__global__ void bucket_scan_kernel(const int* __restrict__ bcnt, int* __restrict__ bbase,
                                   int* __restrict__ bcur, int* __restrict__ row_ptr,
                                   int nb, int n, int e) {
    __shared__ int s[1024];
    int t = threadIdx.x;
    int v = (t < nb) ? bcnt[t] : 0;
    s[t] = v;
    __syncthreads();
    for (int o = 1; o < 1024; o <<= 1) {
        int a = (t >= o) ? s[t - o] : 0;
        __syncthreads();
        s[t] += a;
        __syncthreads();
    }
    if (t < nb) {
        int excl = s[t] - v;
        bbase[t] = excl;
        bcur[t] = excl;
    }
    if (t == 0) {
        bbase[nb] = e;
        row_ptr[n] = e;
    }
}

// ---------------- P1: bucketed scatter of packed edges ----------------
// packed word: (src << BKBITS) | (dst & (BKN-1))

__global__ __launch_bounds__(256) void bucket_fill_kernel(const int* __restrict__ src,
                                                          const int* __restrict__ dst,
                                                          int* __restrict__ bcur,
                                                          unsigned* __restrict__ packed,
                                                          int e, int nb) {
    __shared__ unsigned sw[EPB];
    __shared__ unsigned short sb[EPB];
    __shared__ int hist[NBMAX];
    __shared__ int rbase[NBMAX];
    int t = threadIdx.x;
    for (int i = t; i < nb; i += 256) hist[i] = 0;
    __syncthreads();
    int base = blockIdx.x * EPB;
    for (int k = 0; k < EPB; k += 256) {
        int i = base + k + t;
        if (i < e) {
            int s = src[i];
            int d = dst[i];
            int b = d >> BKBITS;
            sw[k + t] = ((unsigned)s << BKBITS) | (unsigned)(d & (BKN - 1));
            sb[k + t] = (unsigned short)b;
            atomicAdd(&hist[b], 1);
        }
    }
    __syncthreads();
    for (int i = t; i < nb; i += 256) {
        int h = hist[i];
        rbase[i] = h ? atomicAdd(&bcur[i], h) : 0;
        hist[i] = 0;  // reuse as rank counter
    }
    __syncthreads();
    for (int k = 0; k < EPB; k += 256) {
        int i = base + k + t;
        if (i < e) {
            int b = sb[k + t];
            int r = atomicAdd(&hist[b], 1);
            packed[rbase[b] + r] = sw[k + t];
        }
    }
}

// ---------------- P2: per-bucket counting sort -> exact CSR ----------------

__global__ __launch_bounds__(256) void csr_build_kernel(const unsigned* __restrict__ packed,
                                                        const int* __restrict__ bbase,
                                                        int* __restrict__ row_ptr,
                                                        int* __restrict__ esrc, int n) {
    __shared__ unsigned ew[CAP];
    __shared__ int h2[BKN];
    __shared__ int off[BKN];
    int b = blockIdx.x;
    int base = bbase[b];
    int cnt = bbase[b + 1] - base;
    int t = threadIdx.x;
    if (t < BKN) h2[t] = 0;
    __syncthreads();
    bool staged = (cnt <= CAP);
    for (int i = t; i < cnt; i += 256) {
        unsigned w = packed[base + i];
        if (staged) ew[i] = w;
        atomicAdd(&h2[w & (BKN - 1)], 1);
    }
    __syncthreads();
    int v = 0;
    if (t < BKN) {
        v = h2[t];
        off[t] = v;
    }
    __syncthreads();
    for (int o = 1; o < BKN; o <<= 1) {
        int a = 0;
        if (t < BKN && t >= o) a = off[t - o];
        __syncthreads();
        if (t < BKN) off[t] += a;
        __syncthreads();
    }
    if (t < BKN) {
        int excl = off[t] - v;
        __syncthreads();
        off[t] = excl;
        h2[t] = 0;  // reuse as rank counter
    } else {
        __syncthreads();
    }
    __syncthreads();
    int node = b * BKN + t;
    if (t < BKN && node < n) row_ptr[node] = base + off[t];
    for (int i = t; i < cnt; i += 256) {
        unsigned w = staged ? ew[i] : packed[base + i];
        int dl = w & (BKN - 1);
        int r = atomicAdd(&h2[dl], 1);
        esrc[base + off[dl] + r] = (int)(w >> BKBITS);
    }
}

// ---------------- input projection: h = x @ w_in.T + b_in (bf16 out) ----------------

__global__ void input_proj_kernel(const float* __restrict__ x, const float* __restrict__ w_in,
                                  const float* __restrict__ b_in,
                                  unsigned short* __restrict__ h, int n) {
    __shared__ float sw[DIM * INDIM];
    __shared__ float sb[DIM];
    int t = threadIdx.x;
    if (t < DIM * INDIM) sw[t] = w_in[t];
    if (t < DIM) sb[t] = b_in[t];
    __syncthreads();
    int idx = blockIdx.x * 256 + t;
    int node = idx >> 5;
    int d = idx & 31;
    if (node < n) {
        const float* xr = x + (size_t)node * INDIM;
        float acc = sb[d];
#pragma unroll
        for (int k = 0; k < INDIM; k++) acc = fmaf(xr[k], sw[d * INDIM + k], acc);
        h[(size_t)node * DIM + d] = f2bf(acc);
    }
}

// ---------------- fused layer: gather-mean + SAGEConv + ReLU + LayerNorm ----------------
// 32 nodes/block, 128 threads. Phase 1: 4 threads/node (thread q owns dims [8q,8q+8)),
// 8-wide pull gather with edge-id software pipeline. Phase 2: dual matvec with both
// weight matrices in registers (loaded after the barrier), ReLU + LN, direct store.

template <int LAST>
__global__ __launch_bounds__(128, 4) void layer_fused_kernel(
    const int* __restrict__ row_ptr, const int* __restrict__ esrc,
    const unsigned short* __restrict__ h_in,
    unsigned short* __restrict__ h_out_bf, float* __restrict__ out_f32,
    const float* __restrict__ wl, const float* __restrict__ bl,
    const float* __restrict__ wr, const float* __restrict__ gamma,
    const float* __restrict__ beta, int n) {
    __shared__ float sAgg[32][DIM];
    __shared__ float sSelf[32][DIM];

    int t = threadIdx.x;
    int d = t & 31;

    // ---- phase 1: gather ----
    int nd = t >> 2;  // 0..31
    int q = t & 3;
    int node = blockIdx.x * 32 + nd;
    const uint4* hv = (const uint4*)h_in;  // row = 4 x uint4 (64 B)

    if (node < n) {
        {
            uint4 v = hv[(size_t)node * 4 + q];
            float4 f0 = make_float4(bf2f_lo(v.x), bf2f_hi(v.x), bf2f_lo(v.y), bf2f_hi(v.y));
            float4 f1 = make_float4(bf2f_lo(v.z), bf2f_hi(v.z), bf2f_lo(v.w), bf2f_hi(v.w));
            *(float4*)&sSelf[nd][q * 8] = f0;
            *(float4*)&sSelf[nd][q * 8 + 4] = f1;
        }
        int rs = row_ptr[node];
        int re = row_ptr[node + 1];
        float a0 = 0.f, a1 = 0.f, a2 = 0.f, a3 = 0.f, a4 = 0.f, a5 = 0.f, a6 = 0.f, a7 = 0.f;
        int j = rs;
        int i0, i1, i2, i3, i4, i5, i6, i7;
        bool have = (j + 8 <= re);
        if (have) {
            i0 = esrc[j];     i1 = esrc[j + 1]; i2 = esrc[j + 2]; i3 = esrc[j + 3];
            i4 = esrc[j + 4]; i5 = esrc[j + 5]; i6 = esrc[j + 6]; i7 = esrc[j + 7];
        }
        while (have) {
            int jn = j + 8;
            bool haven = (jn + 8 <= re);
            int t0, t1, t2, t3, t4, t5, t6, t7;
            if (haven) {  // prefetch next ids while gathering current rows
                t0 = esrc[jn];     t1 = esrc[jn + 1]; t2 = esrc[jn + 2]; t3 = esrc[jn + 3];
                t4 = esrc[jn + 4]; t5 = esrc[jn + 5]; t6 = esrc[jn + 6]; t7 = esrc[jn + 7];
            }
            uint4 v0 = hv[(size_t)i0 * 4 + q];
            uint4 v1 = hv[(size_t)i1 * 4 + q];
            uint4 v2 = hv[(size_t)i2 * 4 + q];
            uint4 v3 = hv[(size_t)i3 * 4 + q];
            uint4 v4 = hv[(size_t)i4 * 4 + q];
            uint4 v5 = hv[(size_t)i5 * 4 + q];
            uint4 v6 = hv[(size_t)i6 * 4 + q];
            uint4 v7 = hv[(size_t)i7 * 4 + q];
            a0 += bf2f_lo(v0.x); a1 += bf2f_hi(v0.x); a2 += bf2f_lo(v0.y); a3 += bf2f_hi(v0.y);
            a4 += bf2f_lo(v0.z); a5 += bf2f_hi(v0.z); a6 += bf2f_lo(v0.w); a7 += bf2f_hi(v0.w);
            a0 += bf2f_lo(v1.x); a1 += bf2f_hi(v1.x); a2 += bf2f_lo(v1.y); a3 += bf2f_hi(v1.y);
            a4 += bf2f_lo(v1.z); a5 += bf2f_hi(v1.z); a6 += bf2f_lo(v1.w); a7 += bf2f_hi(v1.w);
            a0 += bf2f_lo(v2.x); a1 += bf2f_hi(v2.x); a2 += bf2f_lo(v2.y); a3 += bf2f_hi(v2.y);
            a4 += bf2f_lo(v2.z); a5 += bf2f_hi(v2.z); a6 += bf2f_lo(v2.w); a7 += bf2f_hi(v2.w);
            a0 += bf2f_lo(v3.x); a1 += bf2f_hi(v3.x); a2 += bf2f_lo(v3.y); a3 += bf2f_hi(v3.y);
            a4 += bf2f_lo(v3.z); a5 += bf2f_hi(v3.z); a6 += bf2f_lo(v3.w); a7 += bf2f_hi(v3.w);
            a0 += bf2f_lo(v4.x); a1 += bf2f_hi(v4.x); a2 += bf2f_lo(v4.y); a3 += bf2f_hi(v4.y);
            a4 += bf2f_lo(v4.z); a5 += bf2f_hi(v4.z); a6 += bf2f_lo(v4.w); a7 += bf2f_hi(v4.w);
            a0 += bf2f_lo(v5.x); a1 += bf2f_hi(v5.x); a2 += bf2f_lo(v5.y); a3 += bf2f_hi(v5.y);
            a4 += bf2f_lo(v5.z); a5 += bf2f_hi(v5.z); a6 += bf2f_lo(v5.w); a7 += bf2f_hi(v5.w);
            a0 += bf2f_lo(v6.x); a1 += bf2f_hi(v6.x); a2 += bf2f_lo(v6.y); a3 += bf2f_hi(v6.y);
            a4 += bf2f_lo(v6.z); a5 += bf2f_hi(v6.z); a6 += bf2f_lo(v6.w); a7 += bf2f_hi(v6.w);
            a0 += bf2f_lo(v7.x); a1 += bf2f_hi(v7.x); a2 += bf2f_lo(v7.y); a3 += bf2f_hi(v7.y);
            a4 += bf2f_lo(v7.z); a5 += bf2f_hi(v7.z); a6 += bf2f_lo(v7.w); a7 += bf2f_hi(v7.w);
            j = jn;
            have = haven;
            if (haven) {
                i0 = t0; i1 = t1; i2 = t2; i3 = t3; i4 = t4; i5 = t5; i6 = t6; i7 = t7;
            }
        }
        for (; j < re; ++j) {
            int s = esrc[j];
            uint4 v = hv[(size_t)s * 4 + q];
            a0 += bf2f_lo(v.x); a1 += bf2f_hi(v.x); a2 += bf2f_lo(v.y); a3 += bf2f_hi(v.y);
            a4 += bf2f_lo(v.z); a5 += bf2f_hi(v.z); a6 += bf2f_lo(v.w); a7 += bf2f_hi(v.w);
        }
        float iv = 1.f / fmaxf((float)(re - rs), 1.f);
        float4 f0 = make_float4(a0 * iv, a1 * iv, a2 * iv, a3 * iv);
        float4 f1 = make_float4(a4 * iv, a5 * iv, a6 * iv, a7 * iv);
        *(float4*)&sAgg[nd][q * 8] = f0;
        *(float4*)&sAgg[nd][q * 8 + 4] = f1;
    }
    __syncthreads();

    // ---- phase 2: combine + ReLU + LN (weights loaded here, after the barrier) ----
    float wlr[DIM], wrr[DIM];
    {
        const float4* p1 = (const float4*)(wl + (size_t)d * DIM);
        const float4* p2 = (const float4*)(wr + (size_t)d * DIM);
#pragma unroll
        for (int qq = 0; qq < 8; qq++) {
            float4 a = p1[qq];
            wlr[4 * qq] = a.x; wlr[4 * qq + 1] = a.y; wlr[4 * qq + 2] = a.z; wlr[4 * qq + 3] = a.w;
            float4 c = p2[qq];
            wrr[4 * qq] = c.x; wrr[4 * qq + 1] = c.y; wrr[4 * qq + 2] = c.z; wrr[4 * qq + 3] = c.w;
        }
    }
    float bias = bl[d], g = gamma[d], be = beta[d];

#pragma unroll
    for (int it = 0; it < 8; ++it) {
        int ln = it * 4 + (t >> 5);           // local node 0..31
        int nodec = blockIdx.x * 32 + ln;
        if (nodec < n) {
            float o = bias;
            const float* va = sAgg[ln];
            const float* vs = sSelf[ln];
#pragma unroll
            for (int qq = 0; qq < 8; qq++) {
                float4 a = *(const float4*)&va[qq * 4];
                float4 s = *(const float4*)&vs[qq * 4];
                o = fmaf(a.x, wlr[4 * qq], o);     o = fmaf(s.x, wrr[4 * qq], o);
                o = fmaf(a.y, wlr[4 * qq + 1], o); o = fmaf(s.y, wrr[4 * qq + 1], o);
                o = fmaf(a.z, wlr[4 * qq + 2], o); o = fmaf(s.z, wrr[4 * qq + 2], o);
                o = fmaf(a.w, wlr[4 * qq + 3], o); o = fmaf(s.w, wrr[4 * qq + 3], o);
            }
            float out = fmaxf(o, 0.f);
            float sum = out, sq = out * out;
#pragma unroll
            for (int off = 16; off > 0; off >>= 1) {
                sum += __shfl_xor(sum, off, 32);
                sq += __shfl_xor(sq, off, 32);
            }
            float mu = sum * (1.f / 32.f);
            float var = fmaxf(sq * (1.f / 32.f) - mu * mu, 0.f);
            float r = rsqrtf(var + 1e-5f);
            float res = (out - mu) * r * g + be;
            if (LAST) out_f32[(size_t)nodec * DIM + d] = res;
            else      h_out_bf[(size_t)nodec * DIM + d] = f2bf(res);
        }
    }
}

// ---------------- launch ----------------

extern "C" void kernel_launch(void* const* d_in, const int* in_sizes, int n_in,
                              void* d_out, int out_size, void* d_ws, size_t ws_size,
                              hipStream_t stream) {
    const float* x = (const float*)d_in[0];
    const int* ei = (const int*)d_in[1];
    const float* w_in = (const float*)d_in[2];
    const float* b_in = (const float*)d_in[3];
    const float* w_l = (const float*)d_in[4];
    const float* b_l = (const float*)d_in[5];
    const float* w_r = (const float*)d_in[6];
    const float* gamma = (const float*)d_in[7];
    const float* beta = (const float*)d_in[8];

    int n = in_sizes[0] / INDIM;
    int e = in_sizes[1] / 2;
    int L = in_sizes[4] / (DIM * DIM);
    const int* src = ei;
    const int* dst = ei + e;
    int nb = (n + BKN - 1) >> BKBITS;  // 128-node buckets (782 for N=100000)

    // workspace carve (~21.7 MB)
    char* w = (char*)d_ws;
    int* bcnt = (int*)w;               w += (size_t)NBMAX * 4;
    int* bbase = (int*)w;              w += (size_t)(NBMAX + 1) * 4;
    int* bcur = (int*)w;               w += (size_t)NBMAX * 4;
    int* row_ptr = (int*)w;            w += (size_t)(n + 1) * 4;
    int* esrc = (int*)w;               w += (size_t)e * 4;
    unsigned short* h_A = (unsigned short*)w;  w += (size_t)n * DIM * 2;
    unsigned short* h_B = (unsigned short*)w;  w += (size_t)n * DIM * 2;
    // packed (E*4 = 8 MB) aliases h_A+h_B (12.8 MB): dead before input_proj
    unsigned* packed = (unsigned*)h_A;

    int nbE = (e + EPB - 1) / EPB;

    hipMemsetAsync(bcnt, 0, (size_t)nb * 4, stream);
    bucket_count_kernel<<<nbE, 256, 0, stream>>>(dst, bcnt, e, nb);
    bucket_scan_kernel<<<1, 1024, 0, stream>>>(bcnt, bbase, bcur, row_ptr, nb, n, e);
    bucket_fill_kernel<<<nbE, 256, 0, stream>>>(src, dst, bcur, packed, e, nb);
    csr_build_kernel<<<nb, 256, 0, stream>>>(packed, bbase, row_ptr, esrc, n);

    input_proj_kernel<<<(n * DIM + 255) / 256, 256, 0, stream>>>(x, w_in, b_in, h_A, n);

    // L=3: A->B, B->A, A->d_out
    unsigned short* bufs[2] = {h_A, h_B};
    int nbF = (n + 31) / 32;
    for (int i = 0; i < L; i++) {
        const unsigned short* hin = bufs[i & 1];
        unsigned short* hout = bufs[(i + 1) & 1];
        const float* wl = w_l + (size_t)i * DIM * DIM;
        const float* bl = b_l + (size_t)i * DIM;
        const float* wr = w_r + (size_t)i * DIM * DIM;
        if (i == L - 1)
            layer_fused_kernel<1><<<nbF, 128, 0, stream>>>(row_ptr, esrc, hin, nullptr,
                                                           (float*)d_out, wl, bl, wr,
                                                           gamma, beta, n);
        else
            layer_fused_kernel<0><<<nbF, 128, 0, stream>>>(row_ptr, esrc, hin, hout,
                                                           nullptr, wl, bl, wr,
                                                           gamma, beta, n);
    }
}